// Round 4
// baseline (4853.059 us; speedup 1.0000x reference)
//
#include <hip/hip_runtime.h>
#include <hip/hip_bf16.h>

// RadarTpaLSTM: 3-layer LSTM (B=1024,T=64,HD=512) + conv-attention head.
// Round 8: persistent dataflow kernel (retry of R7 with hardened innards).
//  - ONE kernel for the whole LSTM wavefront. 384 blocks = (layer,nt,mt),
//    each persists for all 64 timesteps. __launch_bounds__(256,2) + 64KB LDS
//    -> 2 blocks/CU -> all 384 co-resident (capacity 512). Flags are
//    mt-local, blocks dispatch in bid order => even reduced residency
//    cannot deadlock (lowest incomplete mt-group is closed + resident).
//  - R7's raw s_barrier / counted-vmcnt pipeline REMOVED: round-2 A/B showed
//    it null. Persistent loop uses the round-1-verified structure: plain
//    __syncthreads dbuf (STAGE(ch+1) issued before MFMA(ch)).
//  - Flags (agent-scope atomics in workspace):
//      ready[l][t][mt] (16 producers nt') "h rows [128mt..) of (l,t) done"
//      done[l][slot][mt] monotonic read counters for the depth-4 h ring
//        (32 readers per slot epoch; producer at t>=4 waits done>=32*(t>>2)).
//  - c-state in registers across all t; h layers 0/1 in depth-4 ring (8MB);
//    layer 2 writes per-t ys (no WAR). bid=mt*48+g keeps a W panel's 8
//    mt-blocks on one XCD (bid%8=g%8) -> W stays L2-resident across t.
//  - k3_out folded: out[b] = concat[b]*(outW@lin2W) + const (prep_fw).
// Fragment layout (single source of truth, used by prep_w AND lstm_all):
//   B-tile (128 perm-cols x 64 k) per (layer,nt,ch): frag fb = nb*2+kk,
//   elem (fb, lane, j) = W[permcol = nt*128 + nb*16 + (lane&15)]
//                         [k = ch*64 + kk*32 + (lane>>4)*8 + j]
//   perm-col win = nb*16+c: half=nb>>2, gate=nb&3, j_hid = nt*32+half*16+c,
//   orig row = gate*512 + j_hid.  (gate order i,f,g,o)
//   A-tile (128 rows x 64 k): frag fa = mb*2+kk,
//   elem = A[row = b0 + mb*16 + (lane&15)][k = kof + kk*32 + (lane>>4)*8 + j]

typedef short v8s __attribute__((ext_vector_type(8)));
typedef float v4f __attribute__((ext_vector_type(4)));
typedef __hip_bfloat16 bf16;

#define B_   1024
#define T_   64
#define D_   512
#define HD_  512

__device__ __forceinline__ float sigm(float v) { return 1.0f / (1.0f + __expf(-v)); }
__device__ __forceinline__ float tanh_(float v) { return 2.0f / (1.0f + __expf(-2.0f * v)) - 1.0f; }
__device__ __forceinline__ float b2f(bf16 v) { return __bfloat162float(v); }
__device__ __forceinline__ float bu2f(ushort u) {
  union { unsigned i; float f; } x; x.i = ((unsigned)u) << 16; return x.f;
}

// load 8 fp32, round to bf16, store 16B
__device__ __forceinline__ void cvt_store8(ushort* dst, const float* src) {
  float4 a = *(const float4*)src;
  float4 b = *(const float4*)(src + 4);
  bf16 h[8] = {__float2bfloat16(a.x), __float2bfloat16(a.y),
               __float2bfloat16(a.z), __float2bfloat16(a.w),
               __float2bfloat16(b.x), __float2bfloat16(b.y),
               __float2bfloat16(b.z), __float2bfloat16(b.w)};
  *(uint4*)dst = *(const uint4*)h;
}

// async global->LDS, 16B per lane; lds base must be wave-uniform.
__device__ __forceinline__ void glds16(const bf16* g, ushort* l) {
  __builtin_amdgcn_global_load_lds(
      (const __attribute__((address_space(1))) void*)g,
      (__attribute__((address_space(3))) void*)l, 16, 0, 0);
}

// agent-scope flag ops (cross-XCD safe: release writes back L2 to the
// coherence point, acquire invalidates L1/L2 before subsequent reads)
__device__ __forceinline__ void spin_ge(int* p, int tgt) {
  while (__hip_atomic_load(p, __ATOMIC_ACQUIRE, __HIP_MEMORY_SCOPE_AGENT) < tgt)
    __builtin_amdgcn_s_sleep(4);
}
__device__ __forceinline__ void sig(int* p) {
  __hip_atomic_fetch_add(p, 1, __ATOMIC_RELEASE, __HIP_MEMORY_SCOPE_AGENT);
}

// ---------------- workspace layout ----------------
constexpr size_t SZ_YS = (size_t)T_ * B_ * HD_ * 2;     // bf16 [T][B][HD] layer-2 h
constexpr size_t SZ_HR = (size_t)8 * B_ * HD_ * 2;      // h ring: 2 layers x 4 slots
constexpr size_t SZ_ZP = (size_t)B_ * HD_ * 2;          // zero page (bf16)
constexpr size_t SZ_WV = (size_t)B_ * 64 * 4;           // w = htt@lin1^T fp32
constexpr size_t SZ_VB = (size_t)B_ * 64 * 4;           // v accumulator fp32
constexpr size_t SZ_WB = (size_t)3 * 2048 * 1024 * 2;   // frag-ordered bf16 weights
constexpr size_t SZ_KT = (size_t)64 * 64 * 2;           // conv kernel transposed bf16
constexpr size_t SZ_FW = (size_t)640 * 4;               // fused outW@lin2W (+bias)
constexpr size_t SZ_RD = (size_t)3 * 64 * 8 * 4;        // ready[l][t][mt]
constexpr size_t SZ_DN = (size_t)2 * 4 * 8 * 4;         // done[l][slot][mt]
constexpr size_t O_YS = 0;
constexpr size_t O_HR = O_YS + SZ_YS;
constexpr size_t O_ZP = O_HR + SZ_HR;
constexpr size_t O_WV = O_ZP + SZ_ZP;
constexpr size_t O_VB = O_WV + SZ_WV;
constexpr size_t O_WB = O_VB + SZ_VB;
constexpr size_t O_KT = O_WB + SZ_WB;
constexpr size_t O_FW = O_KT + SZ_KT;
constexpr size_t O_RD = O_FW + SZ_FW;
constexpr size_t O_DN = O_RD + SZ_RD;

// ---------------- prep: weights -> fragment-ordered bf16 ----------------
__global__ __launch_bounds__(256) void prep_w(const float* __restrict__ Wih,
                                              const float* __restrict__ Whh,
                                              bf16* __restrict__ Wbuf) {
  int tf = blockIdx.x * 256 + threadIdx.x;  // [0, 786432), 8 elems each
  int group = tf >> 10;                     // (layer, nt, ch)
  int layer = group >> 8, rem = group & 255;
  int nt = rem >> 4, ch = rem & 15;
  int li = tf & 1023;
  int frag = li >> 6, lane = li & 63;
  int nb = frag >> 1, kk = frag & 1;
  int c = lane & 15, q = lane >> 4;
  int half = nb >> 2, gate = nb & 3;
  int j = nt * 32 + half * 16 + c;
  int R = gate * 512 + j;
  int k = (ch & 7) * 64 + kk * 32 + q * 8;
  const float* src = ((ch < 8) ? Wih : Whh) + ((size_t)layer * 2048 + R) * 512 + k;
  cvt_store8((ushort*)(Wbuf + (size_t)tf * 8), src);
}

// conv kernel transpose: kT[t][c] = convW[c][t], bf16
__global__ __launch_bounds__(256) void prep_kt(const float* __restrict__ convW,
                                               bf16* __restrict__ kT) {
  int idx = blockIdx.x * 256 + threadIdx.x;  // < 4096
  int t = idx >> 6, c = idx & 63;
  kT[idx] = __float2bfloat16(t < 63 ? convW[c * 63 + t] : 0.f);
}

// fused output weights: fw[k] = sum_j outW[j]*lin2W[j][k] (k<576);
// fw[576] = outW.lin2b + outb.
__global__ __launch_bounds__(64) void prep_fw(const float* __restrict__ lin2W,
                                              const float* __restrict__ lin2b,
                                              const float* __restrict__ outW,
                                              const float* __restrict__ outb,
                                              float* __restrict__ fw) {
  const int blk = blockIdx.x, tid = threadIdx.x;
  if (blk < 9) {
    const int k = blk * 64 + tid;
    float a = 0.f;
    for (int j = 0; j < 512; ++j) a += outW[j] * lin2W[(size_t)j * 576 + k];
    fw[k] = a;
  } else {
    float a = 0.f;
    for (int j = tid; j < 512; j += 64) a += outW[j] * lin2b[j];
    for (int m = 1; m < 64; m <<= 1) a += __shfl_xor(a, m);
    if (tid == 0) fw[576] = a + outb[0];
  }
}

// ---------------- persistent LSTM dataflow kernel ----------------
// Block (layer,nt,mt): tile 128(batch rows b0=128mt) x 128(perm cols), all t.
// Wave w = (wm=w>>1, wn=w&1): 64x64 (rows wm*64.., n-blocks wn*4 = gates).
// Per t: wait ready -> dbuf 16-ch GEMM (__syncthreads pipeline, round-1
// verified structure) -> signal done(inputs read) -> WAR-wait on own ring
// slot -> cell update (c in regs) -> store h -> __syncthreads -> sig ready.
__global__ __launch_bounds__(256, 2) void lstm_all(
    const float* __restrict__ x, const bf16* __restrict__ Wbuf,
    const float* __restrict__ bih, const float* __restrict__ bhh,
    bf16* __restrict__ ys, bf16* __restrict__ hR, const bf16* __restrict__ zp,
    int* __restrict__ ready, int* __restrict__ done) {
  __shared__ ushort As[2][8192];
  __shared__ ushort Bs[2][8192];

  const int bid = blockIdx.x;
  const int g = bid % 48;   // (layer,nt); bid%8 = g%8 -> W panel XCD-local
  const int mt = bid / 48;
  const int layer = g >> 4, nt = g & 15;
  const int b0 = mt << 7;

  const bf16* Wb = Wbuf + ((size_t)layer * 16 + nt) * 16 * 8192;
  const int tid = threadIdx.x, lane = tid & 63, w = tid >> 6;
  const int c = lane & 15, q = lane >> 4;
  const int wm = w >> 1, wn = w & 1;

  // bias hoist (t-invariant); thread owns hidden col j, gate = ni
  const size_t bb = (size_t)layer * 2048;
  const int j = nt * 32 + wn * 16 + c;
  float bsum[4];
#pragma unroll
  for (int g4 = 0; g4 < 4; ++g4)
    bsum[g4] = bih[bb + g4 * 512 + j] + bhh[bb + g4 * 512 + j];

  // cell state in registers for the whole sequence
  float creg[4][4];
#pragma unroll
  for (int mi = 0; mi < 4; ++mi)
#pragma unroll
    for (int r = 0; r < 4; ++r) creg[mi][r] = 0.f;

  for (int t = 0; t < T_; ++t) {
    // ---- wait for inputs: h^{l-1}[t] rows mt, h^l[t-1] rows mt ----
    if (tid == 0) {
      if (layer > 0) spin_ge(&ready[((layer - 1) * 64 + t) * 8 + mt], 16);
      if (t > 0)     spin_ge(&ready[(layer * 64 + (t - 1)) * 8 + mt], 16);
    }
    __syncthreads();  // tid0's acquire (L1/L2 inv) + barrier orders all reads

    const bf16* srcA0h = (layer > 0)
        ? hR + (size_t)((layer - 1) * 4 + (t & 3)) * (B_ * HD_) : (const bf16*)0;
    const bf16* srcA1 = (t == 0) ? zp
        : (layer < 2 ? hR + (size_t)(layer * 4 + ((t - 1) & 3)) * (B_ * HD_)
                     : ys + (size_t)(t - 1) * (B_ * HD_));

    v4f acc[4][4];
#pragma unroll
    for (int mi = 0; mi < 4; ++mi)
#pragma unroll
      for (int ni = 0; ni < 4; ++ni) acc[mi][ni] = v4f{0.f, 0.f, 0.f, 0.f};

    auto STAGE = [&](int ch, int pb) {
      const int kof = (ch & 7) * 64;
      const bf16* wsrc = Wb + (size_t)ch * 8192;
#pragma unroll
      for (int i = 0; i < 4; ++i) {
        int f = w * 4 + i;
        glds16(wsrc + f * 512 + lane * 8, &Bs[pb][f * 512]);
      }
      if (ch < 8 && layer == 0) {
#pragma unroll
        for (int i = 0; i < 4; ++i) {
          int f = w * 4 + i, mb = f >> 1, k2 = f & 1;
          const float* src = x + (size_t)(b0 + mb * 16 + c) * (T_ * D_) +
                             (size_t)t * D_ + kof + k2 * 32 + q * 8;
          cvt_store8(&As[pb][f * 512 + lane * 8], src);
        }
      } else {
        const bf16* sA = (ch < 8) ? srcA0h : srcA1;
#pragma unroll
        for (int i = 0; i < 4; ++i) {
          int f = w * 4 + i, mb = f >> 1, k2 = f & 1;
          glds16(sA + (size_t)(b0 + mb * 16 + c) * HD_ + kof + k2 * 32 + q * 8,
                 &As[pb][f * 512]);
        }
      }
    };

    STAGE(0, 0);
    __syncthreads();

    for (int ch = 0; ch < 16; ++ch) {
      const int pb = ch & 1;
      if (ch < 15) STAGE(ch + 1, pb ^ 1);  // in flight across the MFMA block
      __builtin_amdgcn_s_setprio(1);
#pragma unroll
      for (int kk = 0; kk < 2; ++kk) {
        v8s af[4], bfr[4];
#pragma unroll
        for (int mi = 0; mi < 4; ++mi)
          af[mi] = *(const v8s*)&As[pb][((wm * 4 + mi) * 2 + kk) * 512 + lane * 8];
#pragma unroll
        for (int ni = 0; ni < 4; ++ni)
          bfr[ni] = *(const v8s*)&Bs[pb][((wn * 4 + ni) * 2 + kk) * 512 + lane * 8];
#pragma unroll
        for (int mi = 0; mi < 4; ++mi)
#pragma unroll
          for (int ni = 0; ni < 4; ++ni)
            acc[mi][ni] = __builtin_amdgcn_mfma_f32_16x16x32_bf16(af[mi], bfr[ni], acc[mi][ni], 0, 0, 0);
      }
      __builtin_amdgcn_s_setprio(0);
      __syncthreads();  // drains this wave's glds16 (vmcnt) + ds_reads (lgkm)
    }

    // Every wave passed the final __syncthreads (vmcnt 0) => all input reads
    // retired; signal read-completion for WAR bookkeeping.
    if (tid == 0) {
      if (layer >= 1) sig(&done[((layer - 1) * 4 + (t & 3)) * 8 + mt]);
      if (layer <= 1 && t >= 1) sig(&done[(layer * 4 + ((t - 1) & 3)) * 8 + mt]);
    }

    // WAR guard: ring slot t&3 was last written at t-4; wait for its 32
    // readers (monotonic target 32*(t>>2), no counter resets).
    if (layer <= 1 && t >= 4 && tid == 0)
      spin_ge(&done[(layer * 4 + (t & 3)) * 8 + mt], 32 * (t >> 2));
    __syncthreads();  // orders every thread's h stores after the WAR spin

    bf16* hw = (layer < 2) ? hR + (size_t)(layer * 4 + (t & 3)) * (B_ * HD_)
                           : ys + (size_t)t * (B_ * HD_);
#pragma unroll
    for (int mi = 0; mi < 4; ++mi) {
#pragma unroll
      for (int r = 0; r < 4; ++r) {
        const int b = b0 + wm * 64 + mi * 16 + q * 4 + r;
        float iv = acc[mi][0][r] + bsum[0];
        float fv = acc[mi][1][r] + bsum[1];
        float gv = acc[mi][2][r] + bsum[2];
        float ov = acc[mi][3][r] + bsum[3];
        float cn = sigm(fv) * creg[mi][r] + sigm(iv) * tanh_(gv);
        float hn = sigm(ov) * tanh_(cn);
        creg[mi][r] = cn;
        hw[(size_t)b * HD_ + j] = __float2bfloat16(hn);
      }
    }

    __syncthreads();  // each wave drains its h stores (vmcnt 0) before signal
    if (tid == 0) sig(&ready[(layer * 64 + t) * 8 + mt]);
  }
}

// ---------------- epilogue: w = htt @ lin1^T + lin1b ----------------
__global__ __launch_bounds__(64) void k0_lin1(const bf16* __restrict__ ys,
                                              const float* __restrict__ lin1W,
                                              const float* __restrict__ lin1b,
                                              float* __restrict__ wv) {
  __shared__ float htt[HD_];
  const int b = blockIdx.x, tid = threadIdx.x;
  for (int i = tid; i < HD_; i += 64)
    htt[i] = b2f(ys[((size_t)(T_ - 1) * B_ + b) * HD_ + i]);
  __syncthreads();
  float a = lin1b[tid];
  const float* wr = lin1W + (size_t)tid * HD_;
  for (int k = 0; k < HD_; k += 4) {
    float4 w4 = *(const float4*)(wr + k);
    a += htt[k] * w4.x + htt[k + 1] * w4.y + htt[k + 2] * w4.z + htt[k + 3] * w4.w;
  }
  wv[(size_t)b * 64 + tid] = a;
}

// ---------------- epilogue: conv einsum + attention (per b) ----------------
__global__ __launch_bounds__(256) void k1_attn(const bf16* __restrict__ ys,
                                               const bf16* __restrict__ kTb,
                                               const float* __restrict__ convb,
                                               const float* __restrict__ wv,
                                               float* __restrict__ vbuf) {
  __shared__ ushort HsL[63 * 512];   // relu(H[b]) bf16
  __shared__ ushort kTL[64 * 64];    // kT[t][c] bf16 (t=63 row zero)
  __shared__ float wsh[64];
  __shared__ float cbs[64];
  const int b = blockIdx.x;
  const int tid = threadIdx.x, lane = tid & 63, w = tid >> 6;

  for (int idx = tid; idx < 63 * 64; idx += 256) {  // 63 rows x 64 groups of 8
    int t = idx >> 6, c8 = idx & 63;
    v8s h = *(const v8s*)(ys + ((size_t)t * B_ + b) * HD_ + c8 * 8);
    v8s r;
#pragma unroll
    for (int e = 0; e < 8; ++e) r[e] = (h[e] & (short)0x8000) ? (short)0 : h[e];
    *(v8s*)&HsL[t * 512 + c8 * 8] = r;
  }
  for (int idx = tid; idx < 512; idx += 256)
    *(v8s*)&kTL[idx * 8] = *(const v8s*)(kTb + idx * 8);
  if (tid < 64) { wsh[tid] = wv[(size_t)b * 64 + tid]; cbs[tid] = convb[tid]; }
  __syncthreads();

  const int ci = lane >> 3, fi = lane & 7;
#pragma unroll
  for (int fgi = 0; fgi < 2; ++fgi) {
    const int fg = w * 2 + fgi, f0 = fg << 6;
    float acc[8][8];
#pragma unroll
    for (int i = 0; i < 8; ++i)
#pragma unroll
      for (int jx = 0; jx < 8; ++jx) acc[i][jx] = 0.f;
    for (int t = 0; t < 63; ++t) {
      v8s k8 = *(const v8s*)&kTL[t * 64 + ci * 8];
      v8s h8 = *(const v8s*)&HsL[t * 512 + f0 + fi * 8];
      float av[8], hv[8];
#pragma unroll
      for (int e = 0; e < 8; ++e) { av[e] = bu2f((ushort)k8[e]); hv[e] = bu2f((ushort)h8[e]); }
#pragma unroll
      for (int i = 0; i < 8; ++i)
#pragma unroll
        for (int jx = 0; jx < 8; ++jx) acc[i][jx] += av[i] * hv[jx];
    }
#pragma unroll
    for (int i = 0; i < 8; ++i)
#pragma unroll
      for (int jx = 0; jx < 8; ++jx)
        acc[i][jx] = fmaxf(acc[i][jx] + cbs[ci * 8 + i], 0.f);

    float vp[8];
#pragma unroll
    for (int jx = 0; jx < 8; ++jx) vp[jx] = 0.f;
#pragma unroll
    for (int i = 0; i < 8; ++i) {
      float sp = 0.f;
#pragma unroll
      for (int jx = 0; jx < 8; ++jx) sp += acc[i][jx] * wsh[fi * 8 + jx];
      sp += __shfl_xor(sp, 1); sp += __shfl_xor(sp, 2); sp += __shfl_xor(sp, 4);
      float al = sigm(sp);
#pragma unroll
      for (int jx = 0; jx < 8; ++jx) vp[jx] += al * acc[i][jx];
    }
#pragma unroll
    for (int jx = 0; jx < 8; ++jx) {
      vp[jx] += __shfl_xor(vp[jx], 8);
      vp[jx] += __shfl_xor(vp[jx], 16);
      vp[jx] += __shfl_xor(vp[jx], 32);
    }
    if (ci == 0)
#pragma unroll
      for (int jx = 0; jx < 8; ++jx)
        atomicAdd(&vbuf[(size_t)b * 64 + fi * 8 + jx], vp[jx]);
  }
}

// ---------------- epilogue: out[b] = [htt,v] . fw + fw[576] ----------------
__global__ __launch_bounds__(64) void k3_out(const bf16* __restrict__ ys,
                                             const float* __restrict__ vbuf,
                                             const float* __restrict__ fw,
                                             float* __restrict__ out) {
  const int b = blockIdx.x, tid = threadIdx.x;
  v8s h = *(const v8s*)(ys + ((size_t)(T_ - 1) * B_ + b) * HD_ + tid * 8);
  const float4 w4a = *(const float4*)(fw + tid * 8);
  const float4 w4b = *(const float4*)(fw + tid * 8 + 4);
  float a = bu2f((ushort)h[0]) * w4a.x + bu2f((ushort)h[1]) * w4a.y +
            bu2f((ushort)h[2]) * w4a.z + bu2f((ushort)h[3]) * w4a.w +
            bu2f((ushort)h[4]) * w4b.x + bu2f((ushort)h[5]) * w4b.y +
            bu2f((ushort)h[6]) * w4b.z + bu2f((ushort)h[7]) * w4b.w;
  a += vbuf[(size_t)b * 64 + tid] * fw[512 + tid];
  for (int m = 1; m < 64; m <<= 1) a += __shfl_xor(a, m);
  if (tid == 0) out[b] = a + fw[576];
}

// ---------------- launch ----------------
extern "C" void kernel_launch(void* const* d_in, const int* in_sizes, int n_in,
                              void* d_out, int out_size, void* d_ws, size_t ws_size,
                              hipStream_t stream) {
  const float* x     = (const float*)d_in[0];
  const float* Wih   = (const float*)d_in[1];
  const float* Whh   = (const float*)d_in[2];
  const float* bih   = (const float*)d_in[3];
  const float* bhh   = (const float*)d_in[4];
  const float* convW = (const float*)d_in[5];
  const float* convb = (const float*)d_in[6];
  const float* lin1W = (const float*)d_in[7];
  const float* lin1b = (const float*)d_in[8];
  const float* lin2W = (const float*)d_in[9];
  const float* lin2b = (const float*)d_in[10];
  const float* outW  = (const float*)d_in[11];
  const float* outb  = (const float*)d_in[12];

  char* ws = (char*)d_ws;
  bf16*  ys    = (bf16*)(ws + O_YS);
  bf16*  hR    = (bf16*)(ws + O_HR);
  bf16*  zp    = (bf16*)(ws + O_ZP);
  float* wv    = (float*)(ws + O_WV);
  float* vbuf  = (float*)(ws + O_VB);
  bf16*  Wbuf  = (bf16*)(ws + O_WB);
  bf16*  kTb   = (bf16*)(ws + O_KT);
  float* fwv   = (float*)(ws + O_FW);
  int*   ready = (int*)(ws + O_RD);
  int*   done  = (int*)(ws + O_DN);

  hipMemsetAsync((void*)zp, 0, SZ_ZP, stream);
  hipMemsetAsync(vbuf, 0, SZ_VB, stream);
  hipMemsetAsync(ready, 0, SZ_RD, stream);
  hipMemsetAsync(done, 0, SZ_DN, stream);

  prep_w<<<3072, 256, 0, stream>>>(Wih, Whh, Wbuf);
  prep_kt<<<16, 256, 0, stream>>>(convW, kTb);
  prep_fw<<<10, 64, 0, stream>>>(lin2W, lin2b, outW, outb, fwv);

  // one persistent dataflow kernel replaces 66 wavefront launches
  lstm_all<<<384, 256, 0, stream>>>(x, Wbuf, bih, bhh, ys, hR, zp, ready, done);

  k0_lin1<<<B_, 64, 0, stream>>>(ys, lin1W, lin1b, wv);
  k1_attn<<<B_, 256, 0, stream>>>(ys, kTb, convb, wv, vbuf);
  k3_out<<<B_, 64, 0, stream>>>(ys, vbuf, fwv, (float*)d_out);
}

// Round 5
// 2905.006 us; speedup vs baseline: 1.6706x; 1.6706x over previous
//
#include <hip/hip_runtime.h>
#include <hip/hip_bf16.h>

// RadarTpaLSTM: 3-layer LSTM (B=1024,T=64,HD=512) + conv-attention head.
// Round 9: launch-based wavefront (persistent R7/R8 abandoned: 4.85ms,
// dependency-serialized vs memory). Traffic cut per R4 counters:
//  - lstm_stage tiles 128 rows x 256 cols (TWO W panels per block):
//    A-redundancy 16x->8x, per-stage bytes ~192MB->~100MB.
//  - bid%8 = nt2: all 24 blocks sharing a W panel-pair on one XCD ->
//    W L2-fill once per XCD (96->12 MB/stage W traffic).
//  - prep_x: one-time x fp32[B][T][D] -> bf16 [T][B][D]; layer-0 staging
//    becomes pure glds16 (halves layer-0 A bytes, kills cvt path).
//  - k3_out folded: out[b] = concat[b]*(outW@lin2W) + const (prep_fw).
// Fragment layout (single source of truth, used by prep_w AND lstm_stage):
//   B-tile (128 perm-cols x 64 k) per (layer,nt,ch): frag fb = nb*2+kk,
//   elem (fb, lane, j) = W[permcol = nt*128 + nb*16 + (lane&15)]
//                         [k = ch*64 + kk*32 + (lane>>4)*8 + j]
//   perm-col win = nb*16+c: half=nb>>2, gate=nb&3, j_hid = nt*32+half*16+c,
//   orig row = gate*512 + j_hid.  (gate order i,f,g,o)
//   A-tile (128 rows x 64 k): frag fa = mb*2+kk,
//   elem = A[row = b0 + mb*16 + (lane&15)][k = kof + kk*32 + (lane>>4)*8 + j]

typedef short v8s __attribute__((ext_vector_type(8)));
typedef float v4f __attribute__((ext_vector_type(4)));
typedef __hip_bfloat16 bf16;

#define B_   1024
#define T_   64
#define D_   512
#define HD_  512

__device__ __forceinline__ float sigm(float v) { return 1.0f / (1.0f + __expf(-v)); }
__device__ __forceinline__ float tanh_(float v) { return 2.0f / (1.0f + __expf(-2.0f * v)) - 1.0f; }
__device__ __forceinline__ float b2f(bf16 v) { return __bfloat162float(v); }
__device__ __forceinline__ float bu2f(ushort u) {
  union { unsigned i; float f; } x; x.i = ((unsigned)u) << 16; return x.f;
}

// load 8 fp32, round to bf16, store 16B
__device__ __forceinline__ void cvt_store8(ushort* dst, const float* src) {
  float4 a = *(const float4*)src;
  float4 b = *(const float4*)(src + 4);
  bf16 h[8] = {__float2bfloat16(a.x), __float2bfloat16(a.y),
               __float2bfloat16(a.z), __float2bfloat16(a.w),
               __float2bfloat16(b.x), __float2bfloat16(b.y),
               __float2bfloat16(b.z), __float2bfloat16(b.w)};
  *(uint4*)dst = *(const uint4*)h;
}

// async global->LDS, 16B per lane; lds base must be wave-uniform.
__device__ __forceinline__ void glds16(const bf16* g, ushort* l) {
  __builtin_amdgcn_global_load_lds(
      (const __attribute__((address_space(1))) void*)g,
      (__attribute__((address_space(3))) void*)l, 16, 0, 0);
}

// ---------------- workspace layout ----------------
constexpr size_t SZ_YS = (size_t)T_ * B_ * HD_ * 2;     // bf16 [T][B][HD] layer-2 h
constexpr size_t SZ_HB = (size_t)2 * 2 * B_ * HD_ * 2;  // h layers 0/1, dbuf, bf16
constexpr size_t SZ_CB = (size_t)3 * B_ * HD_ * 4;      // c fp32, 3 layers
constexpr size_t SZ_ZP = (size_t)B_ * HD_ * 2;          // zero page (bf16)
constexpr size_t SZ_WV = (size_t)B_ * 64 * 4;           // w = htt@lin1^T fp32
constexpr size_t SZ_VB = (size_t)B_ * 64 * 4;           // v accumulator fp32
constexpr size_t SZ_WB = (size_t)3 * 2048 * 1024 * 2;   // frag-ordered bf16 weights
constexpr size_t SZ_KT = (size_t)64 * 64 * 2;           // conv kernel transposed bf16
constexpr size_t SZ_FW = (size_t)640 * 4;               // fused outW@lin2W (+bias)
constexpr size_t SZ_XB = (size_t)T_ * B_ * D_ * 2;      // x as bf16 [T][B][D]
constexpr size_t O_YS = 0;
constexpr size_t O_HB = O_YS + SZ_YS;
constexpr size_t O_CB = O_HB + SZ_HB;
constexpr size_t O_ZP = O_CB + SZ_CB;
constexpr size_t O_WV = O_ZP + SZ_ZP;
constexpr size_t O_VB = O_WV + SZ_WV;
constexpr size_t O_WB = O_VB + SZ_VB;
constexpr size_t O_KT = O_WB + SZ_WB;
constexpr size_t O_FW = O_KT + SZ_KT;
constexpr size_t O_XB = O_FW + SZ_FW;

// ---------------- prep: weights -> fragment-ordered bf16 ----------------
__global__ __launch_bounds__(256) void prep_w(const float* __restrict__ Wih,
                                              const float* __restrict__ Whh,
                                              bf16* __restrict__ Wbuf) {
  int tf = blockIdx.x * 256 + threadIdx.x;  // [0, 786432), 8 elems each
  int group = tf >> 10;                     // (layer, nt, ch)
  int layer = group >> 8, rem = group & 255;
  int nt = rem >> 4, ch = rem & 15;
  int li = tf & 1023;
  int frag = li >> 6, lane = li & 63;
  int nb = frag >> 1, kk = frag & 1;
  int c = lane & 15, q = lane >> 4;
  int half = nb >> 2, gate = nb & 3;
  int j = nt * 32 + half * 16 + c;
  int R = gate * 512 + j;
  int k = (ch & 7) * 64 + kk * 32 + q * 8;
  const float* src = ((ch < 8) ? Wih : Whh) + ((size_t)layer * 2048 + R) * 512 + k;
  cvt_store8((ushort*)(Wbuf + (size_t)tf * 8), src);
}

// x fp32 [B][T][D] -> bf16 [T][B][D] (one-time; off the recurrent path)
__global__ __launch_bounds__(256) void prep_x(const float* __restrict__ x,
                                              bf16* __restrict__ xb) {
  int idx = blockIdx.x * 256 + threadIdx.x;  // < 4194304, 8 elems each
  int d8 = idx & 63;
  int bt = idx >> 6;
  int b = bt & 1023, t = bt >> 10;
  cvt_store8((ushort*)(xb + ((size_t)t * B_ + b) * D_ + d8 * 8),
             x + ((size_t)b * T_ + t) * D_ + d8 * 8);
}

// conv kernel transpose: kT[t][c] = convW[c][t], bf16
__global__ __launch_bounds__(256) void prep_kt(const float* __restrict__ convW,
                                               bf16* __restrict__ kT) {
  int idx = blockIdx.x * 256 + threadIdx.x;  // < 4096
  int t = idx >> 6, c = idx & 63;
  kT[idx] = __float2bfloat16(t < 63 ? convW[c * 63 + t] : 0.f);
}

// fused output weights: fw[k] = sum_j outW[j]*lin2W[j][k] (k<576);
// fw[576] = outW.lin2b + outb.
__global__ __launch_bounds__(64) void prep_fw(const float* __restrict__ lin2W,
                                              const float* __restrict__ lin2b,
                                              const float* __restrict__ outW,
                                              const float* __restrict__ outb,
                                              float* __restrict__ fw) {
  const int blk = blockIdx.x, tid = threadIdx.x;
  if (blk < 9) {
    const int k = blk * 64 + tid;
    float a = 0.f;
    for (int j = 0; j < 512; ++j) a += outW[j] * lin2W[(size_t)j * 576 + k];
    fw[k] = a;
  } else {
    float a = 0.f;
    for (int j = tid; j < 512; j += 64) a += outW[j] * lin2b[j];
    for (int m = 1; m < 64; m <<= 1) a += __shfl_xor(a, m);
    if (tid == 0) fw[576] = a + outb[0];
  }
}

// ---------------- LSTM stage kernel (128 x 256 tiles) ----------------
// Block: 256 thr / 4 waves; tile = 128 batch rows x 256 perm cols = TWO
// adjacent W panels (nt = nt2*2 + {0,1}). Wave w: wm = w>>1 (row half),
// wn = w&1 (panel). Wave tile 64 rows x 128 cols (full panel): acc[4][8].
// bid = u*8 + nt2 (u = (layer-llo)*8 + mt): bid%8 = nt2 -> the 24 blocks
// (3 layers x 8 mt) sharing panel-pair nt2 land on one XCD -> W L2-fill
// once per XCD per stage.
__global__ __launch_bounds__(256, 1) void lstm_stage(
    const bf16* __restrict__ xb, const bf16* __restrict__ Wbuf,
    const float* __restrict__ bih, const float* __restrict__ bhh,
    bf16* __restrict__ ys, bf16* __restrict__ hbuf, float* __restrict__ cbuf,
    const bf16* __restrict__ zp, int s, int llo) {
  __shared__ ushort As[2][8192];    // 128 rows x 64 k
  __shared__ ushort Bs2[2][16384];  // 2 panels x 16 frags x 512

  const int nt2 = blockIdx.x & 7;
  const int u = blockIdx.x >> 3;
  const int layer = llo + (u >> 3);
  const int mt = u & 7;
  const int t = s - layer;
  const int b0 = mt << 7;
  const int p = s & 1;

  bf16* hw = (layer < 2) ? hbuf + ((size_t)p * 2 + layer) * (B_ * HD_)
                         : ys + (size_t)t * (B_ * HD_);
  const bf16* srcA0 = (layer == 0)
      ? xb + (size_t)t * (B_ * D_)
      : hbuf + ((size_t)(p ^ 1) * 2 + (layer - 1)) * (B_ * HD_);
  const bf16* srcA1 = (layer < 2)
      ? hbuf + ((size_t)(p ^ 1) * 2 + layer) * (B_ * HD_)
      : ((t == 0) ? zp : ys + (size_t)(t - 1) * (B_ * HD_));
  const bf16* Wb0 = Wbuf + ((size_t)layer * 16 + nt2 * 2) * 16 * 8192;
  const bf16* Wb1 = Wb0 + (size_t)16 * 8192;

  const int tid = threadIdx.x, lane = tid & 63, w = tid >> 6;
  const int c = lane & 15, q = lane >> 4;
  const int wm = w >> 1, wn = w & 1;

  v4f acc[4][8];
#pragma unroll
  for (int mi = 0; mi < 4; ++mi)
#pragma unroll
    for (int ni = 0; ni < 8; ++ni) acc[mi][ni] = v4f{0.f, 0.f, 0.f, 0.f};

  auto STAGE = [&](int ch, int pb) {
    const int kof = (ch & 7) * 64;
    const bf16* w0 = Wb0 + (size_t)ch * 8192;
    const bf16* w1 = Wb1 + (size_t)ch * 8192;
    // B: 32 frags over 4 waves (wave-uniform frag index F)
#pragma unroll
    for (int i = 0; i < 8; ++i) {
      int F = w * 8 + i;
      const bf16* src = (F < 16) ? (w0 + F * 512) : (w1 + (F - 16) * 512);
      glds16(src + lane * 8, &Bs2[pb][F * 512]);
    }
    // A: 16 frags over 4 waves
    const bf16* sA = (ch < 8) ? srcA0 : srcA1;
#pragma unroll
    for (int i = 0; i < 4; ++i) {
      int f = w * 4 + i, mb = f >> 1, k2 = f & 1;
      glds16(sA + (size_t)(b0 + mb * 16 + c) * HD_ + kof + k2 * 32 + q * 8,
             &As[pb][f * 512]);
    }
  };

  STAGE(0, 0);
  __syncthreads();

  for (int ch = 0; ch < 16; ++ch) {
    const int pb = ch & 1;
    if (ch < 15) STAGE(ch + 1, pb ^ 1);  // in flight across the MFMA block
    __builtin_amdgcn_s_setprio(1);
#pragma unroll
    for (int kk = 0; kk < 2; ++kk) {
      v8s af[4];
#pragma unroll
      for (int mi = 0; mi < 4; ++mi)
        af[mi] = *(const v8s*)&As[pb][((wm * 4 + mi) * 2 + kk) * 512 + lane * 8];
#pragma unroll
      for (int ni = 0; ni < 8; ++ni) {
        v8s bfr = *(const v8s*)&Bs2[pb][wn * 8192 + (ni * 2 + kk) * 512 + lane * 8];
#pragma unroll
        for (int mi = 0; mi < 4; ++mi)
          acc[mi][ni] = __builtin_amdgcn_mfma_f32_16x16x32_bf16(af[mi], bfr, acc[mi][ni], 0, 0, 0);
      }
    }
    __builtin_amdgcn_s_setprio(0);
    __syncthreads();  // drains this wave's glds16 (vmcnt) + ds_reads (lgkm)
  }

  // ---- in-register cell update. Thread covers panel ntp = nt2*2+wn,
  // cols j = ntp*32 + half*16 + c (half=ni>>2, gate=ni&3),
  // rows b = b0 + wm*64 + mi*16 + q*4 + r ----
  float* cl = cbuf + (size_t)layer * (B_ * HD_);
  const size_t bb = (size_t)layer * 2048;
  const int ntp = nt2 * 2 + wn;
  float bs[2][4];
#pragma unroll
  for (int half = 0; half < 2; ++half) {
    const int jh = ntp * 32 + half * 16 + c;
#pragma unroll
    for (int g4 = 0; g4 < 4; ++g4)
      bs[half][g4] = bih[bb + g4 * 512 + jh] + bhh[bb + g4 * 512 + jh];
  }
#pragma unroll
  for (int mi = 0; mi < 4; ++mi) {
#pragma unroll
    for (int r = 0; r < 4; ++r) {
      const int b = b0 + wm * 64 + mi * 16 + q * 4 + r;
#pragma unroll
      for (int half = 0; half < 2; ++half) {
        const int jh = ntp * 32 + half * 16 + c;
        float iv = acc[mi][half * 4 + 0][r] + bs[half][0];
        float fv = acc[mi][half * 4 + 1][r] + bs[half][1];
        float gv = acc[mi][half * 4 + 2][r] + bs[half][2];
        float ov = acc[mi][half * 4 + 3][r] + bs[half][3];
        size_t off = (size_t)b * HD_ + jh;
        float cprev = cl[off];
        float cn = sigm(fv) * cprev + sigm(iv) * tanh_(gv);
        float hn = sigm(ov) * tanh_(cn);
        cl[off] = cn;
        hw[off] = __float2bfloat16(hn);
      }
    }
  }
}

// ---------------- epilogue: w = htt @ lin1^T + lin1b ----------------
__global__ __launch_bounds__(64) void k0_lin1(const bf16* __restrict__ ys,
                                              const float* __restrict__ lin1W,
                                              const float* __restrict__ lin1b,
                                              float* __restrict__ wv) {
  __shared__ float htt[HD_];
  const int b = blockIdx.x, tid = threadIdx.x;
  for (int i = tid; i < HD_; i += 64)
    htt[i] = b2f(ys[((size_t)(T_ - 1) * B_ + b) * HD_ + i]);
  __syncthreads();
  float a = lin1b[tid];
  const float* wr = lin1W + (size_t)tid * HD_;
  for (int k = 0; k < HD_; k += 4) {
    float4 w4 = *(const float4*)(wr + k);
    a += htt[k] * w4.x + htt[k + 1] * w4.y + htt[k + 2] * w4.z + htt[k + 3] * w4.w;
  }
  wv[(size_t)b * 64 + tid] = a;
}

// ---------------- epilogue: conv einsum + attention (per b) ----------------
__global__ __launch_bounds__(256) void k1_attn(const bf16* __restrict__ ys,
                                               const bf16* __restrict__ kTb,
                                               const float* __restrict__ convb,
                                               const float* __restrict__ wv,
                                               float* __restrict__ vbuf) {
  __shared__ ushort HsL[63 * 512];   // relu(H[b]) bf16
  __shared__ ushort kTL[64 * 64];    // kT[t][c] bf16 (t=63 row zero)
  __shared__ float wsh[64];
  __shared__ float cbs[64];
  const int b = blockIdx.x;
  const int tid = threadIdx.x, lane = tid & 63, w = tid >> 6;

  for (int idx = tid; idx < 63 * 64; idx += 256) {  // 63 rows x 64 groups of 8
    int t = idx >> 6, c8 = idx & 63;
    v8s h = *(const v8s*)(ys + ((size_t)t * B_ + b) * HD_ + c8 * 8);
    v8s r;
#pragma unroll
    for (int e = 0; e < 8; ++e) r[e] = (h[e] & (short)0x8000) ? (short)0 : h[e];
    *(v8s*)&HsL[t * 512 + c8 * 8] = r;
  }
  for (int idx = tid; idx < 512; idx += 256)
    *(v8s*)&kTL[idx * 8] = *(const v8s*)(kTb + idx * 8);
  if (tid < 64) { wsh[tid] = wv[(size_t)b * 64 + tid]; cbs[tid] = convb[tid]; }
  __syncthreads();

  const int ci = lane >> 3, fi = lane & 7;
#pragma unroll
  for (int fgi = 0; fgi < 2; ++fgi) {
    const int fg = w * 2 + fgi, f0 = fg << 6;
    float acc[8][8];
#pragma unroll
    for (int i = 0; i < 8; ++i)
#pragma unroll
      for (int jx = 0; jx < 8; ++jx) acc[i][jx] = 0.f;
    for (int t = 0; t < 63; ++t) {
      v8s k8 = *(const v8s*)&kTL[t * 64 + ci * 8];
      v8s h8 = *(const v8s*)&HsL[t * 512 + f0 + fi * 8];
      float av[8], hv[8];
#pragma unroll
      for (int e = 0; e < 8; ++e) { av[e] = bu2f((ushort)k8[e]); hv[e] = bu2f((ushort)h8[e]); }
#pragma unroll
      for (int i = 0; i < 8; ++i)
#pragma unroll
        for (int jx = 0; jx < 8; ++jx) acc[i][jx] += av[i] * hv[jx];
    }
#pragma unroll
    for (int i = 0; i < 8; ++i)
#pragma unroll
      for (int jx = 0; jx < 8; ++jx)
        acc[i][jx] = fmaxf(acc[i][jx] + cbs[ci * 8 + i], 0.f);

    float vp[8];
#pragma unroll
    for (int jx = 0; jx < 8; ++jx) vp[jx] = 0.f;
#pragma unroll
    for (int i = 0; i < 8; ++i) {
      float sp = 0.f;
#pragma unroll
      for (int jx = 0; jx < 8; ++jx) sp += acc[i][jx] * wsh[fi * 8 + jx];
      sp += __shfl_xor(sp, 1); sp += __shfl_xor(sp, 2); sp += __shfl_xor(sp, 4);
      float al = sigm(sp);
#pragma unroll
      for (int jx = 0; jx < 8; ++jx) vp[jx] += al * acc[i][jx];
    }
#pragma unroll
    for (int jx = 0; jx < 8; ++jx) {
      vp[jx] += __shfl_xor(vp[jx], 8);
      vp[jx] += __shfl_xor(vp[jx], 16);
      vp[jx] += __shfl_xor(vp[jx], 32);
    }
    if (ci == 0)
#pragma unroll
      for (int jx = 0; jx < 8; ++jx)
        atomicAdd(&vbuf[(size_t)b * 64 + fi * 8 + jx], vp[jx]);
  }
}

// ---------------- epilogue: out[b] = [htt,v] . fw + fw[576] ----------------
__global__ __launch_bounds__(64) void k3_out(const bf16* __restrict__ ys,
                                             const float* __restrict__ vbuf,
                                             const float* __restrict__ fw,
                                             float* __restrict__ out) {
  const int b = blockIdx.x, tid = threadIdx.x;
  v8s h = *(const v8s*)(ys + ((size_t)(T_ - 1) * B_ + b) * HD_ + tid * 8);
  const float4 w4a = *(const float4*)(fw + tid * 8);
  const float4 w4b = *(const float4*)(fw + tid * 8 + 4);
  float a = bu2f((ushort)h[0]) * w4a.x + bu2f((ushort)h[1]) * w4a.y +
            bu2f((ushort)h[2]) * w4a.z + bu2f((ushort)h[3]) * w4a.w +
            bu2f((ushort)h[4]) * w4b.x + bu2f((ushort)h[5]) * w4b.y +
            bu2f((ushort)h[6]) * w4b.z + bu2f((ushort)h[7]) * w4b.w;
  a += vbuf[(size_t)b * 64 + tid] * fw[512 + tid];
  for (int m = 1; m < 64; m <<= 1) a += __shfl_xor(a, m);
  if (tid == 0) out[b] = a + fw[576];
}

// ---------------- launch ----------------
extern "C" void kernel_launch(void* const* d_in, const int* in_sizes, int n_in,
                              void* d_out, int out_size, void* d_ws, size_t ws_size,
                              hipStream_t stream) {
  const float* x     = (const float*)d_in[0];
  const float* Wih   = (const float*)d_in[1];
  const float* Whh   = (const float*)d_in[2];
  const float* bih   = (const float*)d_in[3];
  const float* bhh   = (const float*)d_in[4];
  const float* convW = (const float*)d_in[5];
  const float* convb = (const float*)d_in[6];
  const float* lin1W = (const float*)d_in[7];
  const float* lin1b = (const float*)d_in[8];
  const float* lin2W = (const float*)d_in[9];
  const float* lin2b = (const float*)d_in[10];
  const float* outW  = (const float*)d_in[11];
  const float* outb  = (const float*)d_in[12];

  char* ws = (char*)d_ws;
  bf16*  ys   = (bf16*)(ws + O_YS);
  bf16*  hbuf = (bf16*)(ws + O_HB);
  float* cbuf = (float*)(ws + O_CB);
  bf16*  zp   = (bf16*)(ws + O_ZP);
  float* wv   = (float*)(ws + O_WV);
  float* vbuf = (float*)(ws + O_VB);
  bf16*  Wbuf = (bf16*)(ws + O_WB);
  bf16*  kTb  = (bf16*)(ws + O_KT);
  float* fwv  = (float*)(ws + O_FW);
  bf16*  xb   = (bf16*)(ws + O_XB);

  hipMemsetAsync(hbuf, 0, SZ_HB, stream);
  hipMemsetAsync(cbuf, 0, SZ_CB, stream);
  hipMemsetAsync((void*)zp, 0, SZ_ZP, stream);
  hipMemsetAsync(vbuf, 0, SZ_VB, stream);

  prep_w<<<3072, 256, 0, stream>>>(Wih, Whh, Wbuf);
  prep_x<<<16384, 256, 0, stream>>>(x, xb);
  prep_kt<<<16, 256, 0, stream>>>(convW, kTb);
  prep_fw<<<10, 64, 0, stream>>>(lin2W, lin2b, outW, outb, fwv);

  // diagonal wavefront: stage s runs cells (l, t=s-l) for active layers
  for (int s = 0; s < T_ + 3 - 1; ++s) {
    int llo = (s > T_ - 1) ? (s - (T_ - 1)) : 0;
    int lhi = (s < 2) ? s : 2;
    int cnt = lhi - llo + 1;
    lstm_stage<<<cnt * 64, 256, 0, stream>>>(xb, Wbuf, bih, bhh, ys, hbuf,
                                             cbuf, zp, s, llo);
  }

  k0_lin1<<<B_, 64, 0, stream>>>(ys, lin1W, lin1b, wv);
  k1_attn<<<B_, 256, 0, stream>>>(ys, kTb, convb, wv, vbuf);
  k3_out<<<B_, 64, 0, stream>>>(ys, vbuf, fwv, (float*)d_out);
}

// Round 7
// 2102.891 us; speedup vs baseline: 2.3078x; 1.3814x over previous
//
#include <hip/hip_runtime.h>
#include <hip/hip_bf16.h>

// RadarTpaLSTM: 3-layer LSTM (B=1024,T=64,HD=512) + conv-attention head.
// Round 11 == Round 10 resubmit (infra "container failed twice"; R3->R4
// precedent says flake; kernel audited: no spin/raw-barrier/hang source).
// Occupancy push: per-BLOCK staging rate is pinned (~13-19GB/s) across
// R1/R2/R5 variants = m97's per-block rate; stage time scales with wave
// concurrency, not bytes. So: R1's 128x128 tile geometry, but 512-thread /
// 8-wave blocks (wave tile 32x64, acc[2][4], 4 glds16/wave/iter), LDS 64KB
// dbuf -> 2 blocks/CU -> ~12 waves/CU (2x R1). prep_x kept (bf16 x =>
// all-glds16 staging). k3_out folded via prep_fw (R5-verified).
// Fragment layout (single source of truth, used by prep_w AND lstm_stage):
//   B-tile (128 perm-cols x 64 k) per (layer,nt,ch): frag fb = nb*2+kk,
//   elem (fb, lane, j) = W[permcol = nt*128 + nb*16 + (lane&15)]
//                         [k = ch*64 + kk*32 + (lane>>4)*8 + j]
//   perm-col win = nb*16+c: half=nb>>2, gate=nb&3, j_hid = nt*32+half*16+c,
//   orig row = gate*512 + j_hid.  (gate order i,f,g,o)
//   A-tile (128 rows x 64 k): frag fa = mb*2+kk,
//   elem = A[row = b0 + mb*16 + (lane&15)][k = kof + kk*32 + (lane>>4)*8 + j]

typedef short v8s __attribute__((ext_vector_type(8)));
typedef float v4f __attribute__((ext_vector_type(4)));
typedef __hip_bfloat16 bf16;

#define B_   1024
#define T_   64
#define D_   512
#define HD_  512

__device__ __forceinline__ float sigm(float v) { return 1.0f / (1.0f + __expf(-v)); }
__device__ __forceinline__ float tanh_(float v) { return 2.0f / (1.0f + __expf(-2.0f * v)) - 1.0f; }
__device__ __forceinline__ float b2f(bf16 v) { return __bfloat162float(v); }
__device__ __forceinline__ float bu2f(ushort u) {
  union { unsigned i; float f; } x; x.i = ((unsigned)u) << 16; return x.f;
}

// load 8 fp32, round to bf16, store 16B
__device__ __forceinline__ void cvt_store8(ushort* dst, const float* src) {
  float4 a = *(const float4*)src;
  float4 b = *(const float4*)(src + 4);
  bf16 h[8] = {__float2bfloat16(a.x), __float2bfloat16(a.y),
               __float2bfloat16(a.z), __float2bfloat16(a.w),
               __float2bfloat16(b.x), __float2bfloat16(b.y),
               __float2bfloat16(b.z), __float2bfloat16(b.w)};
  *(uint4*)dst = *(const uint4*)h;
}

// async global->LDS, 16B per lane; lds base must be wave-uniform.
__device__ __forceinline__ void glds16(const bf16* g, ushort* l) {
  __builtin_amdgcn_global_load_lds(
      (const __attribute__((address_space(1))) void*)g,
      (__attribute__((address_space(3))) void*)l, 16, 0, 0);
}

// ---------------- workspace layout ----------------
constexpr size_t SZ_YS = (size_t)T_ * B_ * HD_ * 2;     // bf16 [T][B][HD] layer-2 h
constexpr size_t SZ_HB = (size_t)2 * 2 * B_ * HD_ * 2;  // h layers 0/1, dbuf, bf16
constexpr size_t SZ_CB = (size_t)3 * B_ * HD_ * 4;      // c fp32, 3 layers
constexpr size_t SZ_ZP = (size_t)B_ * HD_ * 2;          // zero page (bf16)
constexpr size_t SZ_WV = (size_t)B_ * 64 * 4;           // w = htt@lin1^T fp32
constexpr size_t SZ_VB = (size_t)B_ * 64 * 4;           // v accumulator fp32
constexpr size_t SZ_WB = (size_t)3 * 2048 * 1024 * 2;   // frag-ordered bf16 weights
constexpr size_t SZ_KT = (size_t)64 * 64 * 2;           // conv kernel transposed bf16
constexpr size_t SZ_FW = (size_t)640 * 4;               // fused outW@lin2W (+bias)
constexpr size_t SZ_XB = (size_t)T_ * B_ * D_ * 2;      // x as bf16 [T][B][D]
constexpr size_t O_YS = 0;
constexpr size_t O_HB = O_YS + SZ_YS;
constexpr size_t O_CB = O_HB + SZ_HB;
constexpr size_t O_ZP = O_CB + SZ_CB;
constexpr size_t O_WV = O_ZP + SZ_ZP;
constexpr size_t O_VB = O_WV + SZ_WV;
constexpr size_t O_WB = O_VB + SZ_VB;
constexpr size_t O_KT = O_WB + SZ_WB;
constexpr size_t O_FW = O_KT + SZ_KT;
constexpr size_t O_XB = O_FW + SZ_FW;

// ---------------- prep: weights -> fragment-ordered bf16 ----------------
__global__ __launch_bounds__(256) void prep_w(const float* __restrict__ Wih,
                                              const float* __restrict__ Whh,
                                              bf16* __restrict__ Wbuf) {
  int tf = blockIdx.x * 256 + threadIdx.x;  // [0, 786432), 8 elems each
  int group = tf >> 10;                     // (layer, nt, ch)
  int layer = group >> 8, rem = group & 255;
  int nt = rem >> 4, ch = rem & 15;
  int li = tf & 1023;
  int frag = li >> 6, lane = li & 63;
  int nb = frag >> 1, kk = frag & 1;
  int c = lane & 15, q = lane >> 4;
  int half = nb >> 2, gate = nb & 3;
  int j = nt * 32 + half * 16 + c;
  int R = gate * 512 + j;
  int k = (ch & 7) * 64 + kk * 32 + q * 8;
  const float* src = ((ch < 8) ? Wih : Whh) + ((size_t)layer * 2048 + R) * 512 + k;
  cvt_store8((ushort*)(Wbuf + (size_t)tf * 8), src);
}

// x fp32 [B][T][D] -> bf16 [T][B][D] (one-time; off the recurrent path)
__global__ __launch_bounds__(256) void prep_x(const float* __restrict__ x,
                                              bf16* __restrict__ xb) {
  int idx = blockIdx.x * 256 + threadIdx.x;  // < 4194304, 8 elems each
  int d8 = idx & 63;
  int bt = idx >> 6;
  int b = bt & 1023, t = bt >> 10;
  cvt_store8((ushort*)(xb + ((size_t)t * B_ + b) * D_ + d8 * 8),
             x + ((size_t)b * T_ + t) * D_ + d8 * 8);
}

// conv kernel transpose: kT[t][c] = convW[c][t], bf16
__global__ __launch_bounds__(256) void prep_kt(const float* __restrict__ convW,
                                               bf16* __restrict__ kT) {
  int idx = blockIdx.x * 256 + threadIdx.x;  // < 4096
  int t = idx >> 6, c = idx & 63;
  kT[idx] = __float2bfloat16(t < 63 ? convW[c * 63 + t] : 0.f);
}

// fused output weights: fw[k] = sum_j outW[j]*lin2W[j][k] (k<576);
// fw[576] = outW.lin2b + outb.
__global__ __launch_bounds__(64) void prep_fw(const float* __restrict__ lin2W,
                                              const float* __restrict__ lin2b,
                                              const float* __restrict__ outW,
                                              const float* __restrict__ outb,
                                              float* __restrict__ fw) {
  const int blk = blockIdx.x, tid = threadIdx.x;
  if (blk < 9) {
    const int k = blk * 64 + tid;
    float a = 0.f;
    for (int j = 0; j < 512; ++j) a += outW[j] * lin2W[(size_t)j * 576 + k];
    fw[k] = a;
  } else {
    float a = 0.f;
    for (int j = tid; j < 512; j += 64) a += outW[j] * lin2b[j];
    for (int m = 1; m < 64; m <<= 1) a += __shfl_xor(a, m);
    if (tid == 0) fw[576] = a + outb[0];
  }
}

// ---------------- LSTM stage kernel (8-wave blocks) ----------------
// Block: 512 thr / 8 waves, tile 128(batch) x 128(perm cols).
// Wave w: wn = w&1 (col half, 4 nb), wm = w>>1 (row quarter, 2 mb).
// Wave tile 32 rows x 64 cols: acc[2][4]. Staging: 2 B-frags + 2 A-frags
// per wave per ch (wave-uniform LDS dests). 12 waves/CU avg at 384 blocks.
__global__ __launch_bounds__(512, 4) void lstm_stage(
    const bf16* __restrict__ xb, const bf16* __restrict__ Wbuf,
    const float* __restrict__ bih, const float* __restrict__ bhh,
    bf16* __restrict__ ys, bf16* __restrict__ hbuf, float* __restrict__ cbuf,
    const bf16* __restrict__ zp, int s, int llo) {
  __shared__ ushort As[2][8192];
  __shared__ ushort Bs[2][8192];

  const int layer = llo + (blockIdx.x >> 7);
  const int tile = blockIdx.x & 127;
  const int t = s - layer;
  const int mt = tile >> 4, nt = tile & 15;
  const int b0 = mt << 7;
  const int p = s & 1;

  bf16* hw = (layer < 2) ? hbuf + ((size_t)p * 2 + layer) * (B_ * HD_)
                         : ys + (size_t)t * (B_ * HD_);
  const bf16* srcA0 = (layer == 0)
      ? xb + (size_t)t * (B_ * D_)
      : hbuf + ((size_t)(p ^ 1) * 2 + (layer - 1)) * (B_ * HD_);
  const bf16* srcA1 = (layer < 2)
      ? hbuf + ((size_t)(p ^ 1) * 2 + layer) * (B_ * HD_)
      : ((t == 0) ? zp : ys + (size_t)(t - 1) * (B_ * HD_));
  const bf16* Wb = Wbuf + ((size_t)layer * 16 + nt) * 16 * 8192;

  const int tid = threadIdx.x, lane = tid & 63, w = tid >> 6;
  const int c = lane & 15, q = lane >> 4;
  const int wm = w >> 1, wn = w & 1;

  v4f acc[2][4];
#pragma unroll
  for (int mi = 0; mi < 2; ++mi)
#pragma unroll
    for (int ni = 0; ni < 4; ++ni) acc[mi][ni] = v4f{0.f, 0.f, 0.f, 0.f};

  auto STAGE = [&](int ch, int pb) {
    const int kof = (ch & 7) * 64;
    const bf16* wsrc = Wb + (size_t)ch * 8192;
    const bf16* sA = (ch < 8) ? srcA0 : srcA1;
#pragma unroll
    for (int i = 0; i < 2; ++i) {
      int F = w * 2 + i;
      glds16(wsrc + F * 512 + lane * 8, &Bs[pb][F * 512]);
    }
#pragma unroll
    for (int i = 0; i < 2; ++i) {
      int f = w * 2 + i, mb = f >> 1, k2 = f & 1;
      glds16(sA + (size_t)(b0 + mb * 16 + c) * HD_ + kof + k2 * 32 + q * 8,
             &As[pb][f * 512]);
    }
  };

  STAGE(0, 0);
  __syncthreads();

  for (int ch = 0; ch < 16; ++ch) {
    const int pb = ch & 1;
    if (ch < 15) STAGE(ch + 1, pb ^ 1);  // in flight across the MFMA block
    __builtin_amdgcn_s_setprio(1);
#pragma unroll
    for (int kk = 0; kk < 2; ++kk) {
      v8s af[2], bfr[4];
#pragma unroll
      for (int mi = 0; mi < 2; ++mi)
        af[mi] = *(const v8s*)&As[pb][((wm * 2 + mi) * 2 + kk) * 512 + lane * 8];
#pragma unroll
      for (int ni = 0; ni < 4; ++ni)
        bfr[ni] = *(const v8s*)&Bs[pb][((wn * 4 + ni) * 2 + kk) * 512 + lane * 8];
#pragma unroll
      for (int mi = 0; mi < 2; ++mi)
#pragma unroll
        for (int ni = 0; ni < 4; ++ni)
          acc[mi][ni] = __builtin_amdgcn_mfma_f32_16x16x32_bf16(af[mi], bfr[ni], acc[mi][ni], 0, 0, 0);
    }
    __builtin_amdgcn_s_setprio(0);
    __syncthreads();  // drains this wave's glds16 (vmcnt) + ds_reads (lgkm)
  }

  // ---- in-register cell update: thread owns gates i,f,g,o (ni=gate) at
  // hidden j = nt*32 + wn*16 + c, rows b0 + wm*32 + mi*16 + q*4 + r ----
  float* cl = cbuf + (size_t)layer * (B_ * HD_);
  const size_t bb = (size_t)layer * 2048;
  const int j = nt * 32 + wn * 16 + c;
  float bsum[4];
#pragma unroll
  for (int g4 = 0; g4 < 4; ++g4)
    bsum[g4] = bih[bb + g4 * 512 + j] + bhh[bb + g4 * 512 + j];
#pragma unroll
  for (int mi = 0; mi < 2; ++mi) {
#pragma unroll
    for (int r = 0; r < 4; ++r) {
      const int b = b0 + wm * 32 + mi * 16 + q * 4 + r;
      float iv = acc[mi][0][r] + bsum[0];
      float fv = acc[mi][1][r] + bsum[1];
      float gv = acc[mi][2][r] + bsum[2];
      float ov = acc[mi][3][r] + bsum[3];
      size_t off = (size_t)b * HD_ + j;
      float cprev = cl[off];
      float cn = sigm(fv) * cprev + sigm(iv) * tanh_(gv);
      float hn = sigm(ov) * tanh_(cn);
      cl[off] = cn;
      hw[off] = __float2bfloat16(hn);
    }
  }
}

// ---------------- epilogue: w = htt @ lin1^T + lin1b ----------------
__global__ __launch_bounds__(64) void k0_lin1(const bf16* __restrict__ ys,
                                              const float* __restrict__ lin1W,
                                              const float* __restrict__ lin1b,
                                              float* __restrict__ wv) {
  __shared__ float htt[HD_];
  const int b = blockIdx.x, tid = threadIdx.x;
  for (int i = tid; i < HD_; i += 64)
    htt[i] = b2f(ys[((size_t)(T_ - 1) * B_ + b) * HD_ + i]);
  __syncthreads();
  float a = lin1b[tid];
  const float* wr = lin1W + (size_t)tid * HD_;
  for (int k = 0; k < HD_; k += 4) {
    float4 w4 = *(const float4*)(wr + k);
    a += htt[k] * w4.x + htt[k + 1] * w4.y + htt[k + 2] * w4.z + htt[k + 3] * w4.w;
  }
  wv[(size_t)b * 64 + tid] = a;
}

// ---------------- epilogue: conv einsum + attention (per b) ----------------
__global__ __launch_bounds__(256) void k1_attn(const bf16* __restrict__ ys,
                                               const bf16* __restrict__ kTb,
                                               const float* __restrict__ convb,
                                               const float* __restrict__ wv,
                                               float* __restrict__ vbuf) {
  __shared__ ushort HsL[63 * 512];   // relu(H[b]) bf16
  __shared__ ushort kTL[64 * 64];    // kT[t][c] bf16 (t=63 row zero)
  __shared__ float wsh[64];
  __shared__ float cbs[64];
  const int b = blockIdx.x;
  const int tid = threadIdx.x, lane = tid & 63, w = tid >> 6;

  for (int idx = tid; idx < 63 * 64; idx += 256) {  // 63 rows x 64 groups of 8
    int t = idx >> 6, c8 = idx & 63;
    v8s h = *(const v8s*)(ys + ((size_t)t * B_ + b) * HD_ + c8 * 8);
    v8s r;
#pragma unroll
    for (int e = 0; e < 8; ++e) r[e] = (h[e] & (short)0x8000) ? (short)0 : h[e];
    *(v8s*)&HsL[t * 512 + c8 * 8] = r;
  }
  for (int idx = tid; idx < 512; idx += 256)
    *(v8s*)&kTL[idx * 8] = *(const v8s*)(kTb + idx * 8);
  if (tid < 64) { wsh[tid] = wv[(size_t)b * 64 + tid]; cbs[tid] = convb[tid]; }
  __syncthreads();

  const int ci = lane >> 3, fi = lane & 7;
#pragma unroll
  for (int fgi = 0; fgi < 2; ++fgi) {
    const int fg = w * 2 + fgi, f0 = fg << 6;
    float acc[8][8];
#pragma unroll
    for (int i = 0; i < 8; ++i)
#pragma unroll
      for (int jx = 0; jx < 8; ++jx) acc[i][jx] = 0.f;
    for (int t = 0; t < 63; ++t) {
      v8s k8 = *(const v8s*)&kTL[t * 64 + ci * 8];
      v8s h8 = *(const v8s*)&HsL[t * 512 + f0 + fi * 8];
      float av[8], hv[8];
#pragma unroll
      for (int e = 0; e < 8; ++e) { av[e] = bu2f((ushort)k8[e]); hv[e] = bu2f((ushort)h8[e]); }
#pragma unroll
      for (int i = 0; i < 8; ++i)
#pragma unroll
        for (int jx = 0; jx < 8; ++jx) acc[i][jx] += av[i] * hv[jx];
    }
#pragma unroll
    for (int i = 0; i < 8; ++i)
#pragma unroll
      for (int jx = 0; jx < 8; ++jx)
        acc[i][jx] = fmaxf(acc[i][jx] + cbs[ci * 8 + i], 0.f);

    float vp[8];
#pragma unroll
    for (int jx = 0; jx < 8; ++jx) vp[jx] = 0.f;
#pragma unroll
    for (int i = 0; i < 8; ++i) {
      float sp = 0.f;
#pragma unroll
      for (int jx = 0; jx < 8; ++jx) sp += acc[i][jx] * wsh[fi * 8 + jx];
      sp += __shfl_xor(sp, 1); sp += __shfl_xor(sp, 2); sp += __shfl_xor(sp, 4);
      float al = sigm(sp);
#pragma unroll
      for (int jx = 0; jx < 8; ++jx) vp[jx] += al * acc[i][jx];
    }
#pragma unroll
    for (int jx = 0; jx < 8; ++jx) {
      vp[jx] += __shfl_xor(vp[jx], 8);
      vp[jx] += __shfl_xor(vp[jx], 16);
      vp[jx] += __shfl_xor(vp[jx], 32);
    }
    if (ci == 0)
#pragma unroll
      for (int jx = 0; jx < 8; ++jx)
        atomicAdd(&vbuf[(size_t)b * 64 + fi * 8 + jx], vp[jx]);
  }
}

// ---------------- epilogue: out[b] = [htt,v] . fw + fw[576] ----------------
__global__ __launch_bounds__(64) void k3_out(const bf16* __restrict__ ys,
                                             const float* __restrict__ vbuf,
                                             const float* __restrict__ fw,
                                             float* __restrict__ out) {
  const int b = blockIdx.x, tid = threadIdx.x;
  v8s h = *(const v8s*)(ys + ((size_t)(T_ - 1) * B_ + b) * HD_ + tid * 8);
  const float4 w4a = *(const float4*)(fw + tid * 8);
  const float4 w4b = *(const float4*)(fw + tid * 8 + 4);
  float a = bu2f((ushort)h[0]) * w4a.x + bu2f((ushort)h[1]) * w4a.y +
            bu2f((ushort)h[2]) * w4a.z + bu2f((ushort)h[3]) * w4a.w +
            bu2f((ushort)h[4]) * w4b.x + bu2f((ushort)h[5]) * w4b.y +
            bu2f((ushort)h[6]) * w4b.z + bu2f((ushort)h[7]) * w4b.w;
  a += vbuf[(size_t)b * 64 + tid] * fw[512 + tid];
  for (int m = 1; m < 64; m <<= 1) a += __shfl_xor(a, m);
  if (tid == 0) out[b] = a + fw[576];
}

// ---------------- launch ----------------
extern "C" void kernel_launch(void* const* d_in, const int* in_sizes, int n_in,
                              void* d_out, int out_size, void* d_ws, size_t ws_size,
                              hipStream_t stream) {
  const float* x     = (const float*)d_in[0];
  const float* Wih   = (const float*)d_in[1];
  const float* Whh   = (const float*)d_in[2];
  const float* bih   = (const float*)d_in[3];
  const float* bhh   = (const float*)d_in[4];
  const float* convW = (const float*)d_in[5];
  const float* convb = (const float*)d_in[6];
  const float* lin1W = (const float*)d_in[7];
  const float* lin1b = (const float*)d_in[8];
  const float* lin2W = (const float*)d_in[9];
  const float* lin2b = (const float*)d_in[10];
  const float* outW  = (const float*)d_in[11];
  const float* outb  = (const float*)d_in[12];

  char* ws = (char*)d_ws;
  bf16*  ys   = (bf16*)(ws + O_YS);
  bf16*  hbuf = (bf16*)(ws + O_HB);
  float* cbuf = (float*)(ws + O_CB);
  bf16*  zp   = (bf16*)(ws + O_ZP);
  float* wv   = (float*)(ws + O_WV);
  float* vbuf = (float*)(ws + O_VB);
  bf16*  Wbuf = (bf16*)(ws + O_WB);
  bf16*  kTb  = (bf16*)(ws + O_KT);
  float* fwv  = (float*)(ws + O_FW);
  bf16*  xb   = (bf16*)(ws + O_XB);

  hipMemsetAsync(hbuf, 0, SZ_HB, stream);
  hipMemsetAsync(cbuf, 0, SZ_CB, stream);
  hipMemsetAsync((void*)zp, 0, SZ_ZP, stream);
  hipMemsetAsync(vbuf, 0, SZ_VB, stream);

  prep_w<<<3072, 256, 0, stream>>>(Wih, Whh, Wbuf);
  prep_x<<<16384, 256, 0, stream>>>(x, xb);
  prep_kt<<<16, 256, 0, stream>>>(convW, kTb);
  prep_fw<<<10, 64, 0, stream>>>(lin2W, lin2b, outW, outb, fwv);

  // diagonal wavefront: stage s runs cells (l, t=s-l) for active layers
  for (int s = 0; s < T_ + 3 - 1; ++s) {
    int llo = (s > T_ - 1) ? (s - (T_ - 1)) : 0;
    int lhi = (s < 2) ? s : 2;
    int cnt = lhi - llo + 1;
    lstm_stage<<<cnt * 128, 512, 0, stream>>>(xb, Wbuf, bih, bhh, ys, hbuf,
                                              cbuf, zp, s, llo);
  }

  k0_lin1<<<B_, 64, 0, stream>>>(ys, lin1W, lin1b, wv);
  k1_attn<<<B_, 256, 0, stream>>>(ys, kTb, convb, wv, vbuf);
  k3_out<<<B_, 64, 0, stream>>>(ys, vbuf, fwv, (float*)d_out);
}

// Round 8
// 1967.628 us; speedup vs baseline: 2.4665x; 1.0687x over previous
//
#include <hip/hip_runtime.h>
#include <hip/hip_bf16.h>

// RadarTpaLSTM: 3-layer LSTM (B=1024,T=64,HD=512) + conv-attention head.
// Round 12: occupancy lever to the ceiling. R11 confirmed stage time scales
// with wave concurrency (6->12 waves/CU = -22% total). Now: 64x128 tiles ->
// 768 blocks/stage x 512 thr (8 waves) = 24 waves/CU, EXACTLY 3 blocks/CU
// (perfect balance; 384-block version had 2:1 CU imbalance). LDS 48KB/block
// (A 2x8KB + B 2x16KB) -> 3 blocks/CU fits 160KB. __launch_bounds__(512,6).
// Per-wave staging 3 glds16/iter. W panels stay XCD-local for free:
// bid%8 = (mt*16+nt)%8 = nt%8, invariant over mt.
// prep_x (bf16 x), k3_out folded via prep_fw: as R11.
// Fragment layout (single source of truth, used by prep_w AND lstm_stage):
//   B-tile (128 perm-cols x 64 k) per (layer,nt,ch): frag fb = nb*2+kk,
//   elem (fb, lane, j) = W[permcol = nt*128 + nb*16 + (lane&15)]
//                         [k = ch*64 + kk*32 + (lane>>4)*8 + j]
//   perm-col win = nb*16+c: half=nb>>2, gate=nb&3, j_hid = nt*32+half*16+c,
//   orig row = gate*512 + j_hid.  (gate order i,f,g,o)
//   A-tile (64 rows x 64 k): frag fa = mb*2+kk (mb=0..3),
//   elem = A[row = b0 + mb*16 + (lane&15)][k = kof + kk*32 + (lane>>4)*8 + j]

typedef short v8s __attribute__((ext_vector_type(8)));
typedef float v4f __attribute__((ext_vector_type(4)));
typedef __hip_bfloat16 bf16;

#define B_   1024
#define T_   64
#define D_   512
#define HD_  512

__device__ __forceinline__ float sigm(float v) { return 1.0f / (1.0f + __expf(-v)); }
__device__ __forceinline__ float tanh_(float v) { return 2.0f / (1.0f + __expf(-2.0f * v)) - 1.0f; }
__device__ __forceinline__ float b2f(bf16 v) { return __bfloat162float(v); }
__device__ __forceinline__ float bu2f(ushort u) {
  union { unsigned i; float f; } x; x.i = ((unsigned)u) << 16; return x.f;
}

// load 8 fp32, round to bf16, store 16B
__device__ __forceinline__ void cvt_store8(ushort* dst, const float* src) {
  float4 a = *(const float4*)src;
  float4 b = *(const float4*)(src + 4);
  bf16 h[8] = {__float2bfloat16(a.x), __float2bfloat16(a.y),
               __float2bfloat16(a.z), __float2bfloat16(a.w),
               __float2bfloat16(b.x), __float2bfloat16(b.y),
               __float2bfloat16(b.z), __float2bfloat16(b.w)};
  *(uint4*)dst = *(const uint4*)h;
}

// async global->LDS, 16B per lane; lds base must be wave-uniform.
__device__ __forceinline__ void glds16(const bf16* g, ushort* l) {
  __builtin_amdgcn_global_load_lds(
      (const __attribute__((address_space(1))) void*)g,
      (__attribute__((address_space(3))) void*)l, 16, 0, 0);
}

// ---------------- workspace layout ----------------
constexpr size_t SZ_YS = (size_t)T_ * B_ * HD_ * 2;     // bf16 [T][B][HD] layer-2 h
constexpr size_t SZ_HB = (size_t)2 * 2 * B_ * HD_ * 2;  // h layers 0/1, dbuf, bf16
constexpr size_t SZ_CB = (size_t)3 * B_ * HD_ * 4;      // c fp32, 3 layers
constexpr size_t SZ_ZP = (size_t)B_ * HD_ * 2;          // zero page (bf16)
constexpr size_t SZ_WV = (size_t)B_ * 64 * 4;           // w = htt@lin1^T fp32
constexpr size_t SZ_VB = (size_t)B_ * 64 * 4;           // v accumulator fp32
constexpr size_t SZ_WB = (size_t)3 * 2048 * 1024 * 2;   // frag-ordered bf16 weights
constexpr size_t SZ_KT = (size_t)64 * 64 * 2;           // conv kernel transposed bf16
constexpr size_t SZ_FW = (size_t)640 * 4;               // fused outW@lin2W (+bias)
constexpr size_t SZ_XB = (size_t)T_ * B_ * D_ * 2;      // x as bf16 [T][B][D]
constexpr size_t O_YS = 0;
constexpr size_t O_HB = O_YS + SZ_YS;
constexpr size_t O_CB = O_HB + SZ_HB;
constexpr size_t O_ZP = O_CB + SZ_CB;
constexpr size_t O_WV = O_ZP + SZ_ZP;
constexpr size_t O_VB = O_WV + SZ_WV;
constexpr size_t O_WB = O_VB + SZ_VB;
constexpr size_t O_KT = O_WB + SZ_WB;
constexpr size_t O_FW = O_KT + SZ_KT;
constexpr size_t O_XB = O_FW + SZ_FW;

// ---------------- prep: weights -> fragment-ordered bf16 ----------------
__global__ __launch_bounds__(256) void prep_w(const float* __restrict__ Wih,
                                              const float* __restrict__ Whh,
                                              bf16* __restrict__ Wbuf) {
  int tf = blockIdx.x * 256 + threadIdx.x;  // [0, 786432), 8 elems each
  int group = tf >> 10;                     // (layer, nt, ch)
  int layer = group >> 8, rem = group & 255;
  int nt = rem >> 4, ch = rem & 15;
  int li = tf & 1023;
  int frag = li >> 6, lane = li & 63;
  int nb = frag >> 1, kk = frag & 1;
  int c = lane & 15, q = lane >> 4;
  int half = nb >> 2, gate = nb & 3;
  int j = nt * 32 + half * 16 + c;
  int R = gate * 512 + j;
  int k = (ch & 7) * 64 + kk * 32 + q * 8;
  const float* src = ((ch < 8) ? Wih : Whh) + ((size_t)layer * 2048 + R) * 512 + k;
  cvt_store8((ushort*)(Wbuf + (size_t)tf * 8), src);
}

// x fp32 [B][T][D] -> bf16 [T][B][D] (one-time; off the recurrent path)
__global__ __launch_bounds__(256) void prep_x(const float* __restrict__ x,
                                              bf16* __restrict__ xb) {
  int idx = blockIdx.x * 256 + threadIdx.x;  // < 4194304, 8 elems each
  int d8 = idx & 63;
  int bt = idx >> 6;
  int b = bt & 1023, t = bt >> 10;
  cvt_store8((ushort*)(xb + ((size_t)t * B_ + b) * D_ + d8 * 8),
             x + ((size_t)b * T_ + t) * D_ + d8 * 8);
}

// conv kernel transpose: kT[t][c] = convW[c][t], bf16
__global__ __launch_bounds__(256) void prep_kt(const float* __restrict__ convW,
                                               bf16* __restrict__ kT) {
  int idx = blockIdx.x * 256 + threadIdx.x;  // < 4096
  int t = idx >> 6, c = idx & 63;
  kT[idx] = __float2bfloat16(t < 63 ? convW[c * 63 + t] : 0.f);
}

// fused output weights: fw[k] = sum_j outW[j]*lin2W[j][k] (k<576);
// fw[576] = outW.lin2b + outb.
__global__ __launch_bounds__(64) void prep_fw(const float* __restrict__ lin2W,
                                              const float* __restrict__ lin2b,
                                              const float* __restrict__ outW,
                                              const float* __restrict__ outb,
                                              float* __restrict__ fw) {
  const int blk = blockIdx.x, tid = threadIdx.x;
  if (blk < 9) {
    const int k = blk * 64 + tid;
    float a = 0.f;
    for (int j = 0; j < 512; ++j) a += outW[j] * lin2W[(size_t)j * 576 + k];
    fw[k] = a;
  } else {
    float a = 0.f;
    for (int j = tid; j < 512; j += 64) a += outW[j] * lin2b[j];
    for (int m = 1; m < 64; m <<= 1) a += __shfl_xor(a, m);
    if (tid == 0) fw[576] = a + outb[0];
  }
}

// ---------------- LSTM stage kernel (64x128 tiles, 8-wave blocks) ----------
// Block: 512 thr / 8 waves, tile 64(batch) x 128(perm cols).
// Wave w: wm = w>>1 (mb, 16-row strip), wn = w&1 (col half). acc[1][4].
// Staging: 24 frags (16 B + 8 A) over 8 waves = 3 glds16/wave/iter.
// Grid: cnt*256; tile = mt*16+nt -> bid%8 = nt%8 (W panel XCD-local, free).
// 3 blocks/CU exactly at middle stages -> 24 waves/CU, perfectly balanced.
__global__ __launch_bounds__(512, 6) void lstm_stage(
    const bf16* __restrict__ xb, const bf16* __restrict__ Wbuf,
    const float* __restrict__ bih, const float* __restrict__ bhh,
    bf16* __restrict__ ys, bf16* __restrict__ hbuf, float* __restrict__ cbuf,
    const bf16* __restrict__ zp, int s, int llo) {
  __shared__ ushort As[2][4096];   // 8 frags x 512
  __shared__ ushort Bs[2][8192];   // 16 frags x 512

  const int layer = llo + (blockIdx.x >> 8);
  const int tile = blockIdx.x & 255;
  const int t = s - layer;
  const int mt = tile >> 4, nt = tile & 15;
  const int b0 = mt << 6;
  const int p = s & 1;

  bf16* hw = (layer < 2) ? hbuf + ((size_t)p * 2 + layer) * (B_ * HD_)
                         : ys + (size_t)t * (B_ * HD_);
  const bf16* srcA0 = (layer == 0)
      ? xb + (size_t)t * (B_ * D_)
      : hbuf + ((size_t)(p ^ 1) * 2 + (layer - 1)) * (B_ * HD_);
  const bf16* srcA1 = (layer < 2)
      ? hbuf + ((size_t)(p ^ 1) * 2 + layer) * (B_ * HD_)
      : ((t == 0) ? zp : ys + (size_t)(t - 1) * (B_ * HD_));
  const bf16* Wb = Wbuf + ((size_t)layer * 16 + nt) * 16 * 8192;

  const int tid = threadIdx.x, lane = tid & 63, w = tid >> 6;
  const int c = lane & 15, q = lane >> 4;
  const int wm = w >> 1, wn = w & 1;

  v4f acc[4];
#pragma unroll
  for (int ni = 0; ni < 4; ++ni) acc[ni] = v4f{0.f, 0.f, 0.f, 0.f};

  auto STAGE = [&](int ch, int pb) {
    const int kof = (ch & 7) * 64;
    const bf16* wsrc = Wb + (size_t)ch * 8192;
    const bf16* sA = (ch < 8) ? srcA0 : srcA1;
#pragma unroll
    for (int i = 0; i < 3; ++i) {
      int idx = w * 3 + i;  // 0..23: 0-15 = B frags, 16-23 = A frags
      if (idx < 16) {
        glds16(wsrc + idx * 512 + lane * 8, &Bs[pb][idx * 512]);
      } else {
        int f = idx - 16, mb = f >> 1, k2 = f & 1;
        glds16(sA + (size_t)(b0 + mb * 16 + c) * HD_ + kof + k2 * 32 + q * 8,
               &As[pb][f * 512]);
      }
    }
  };

  STAGE(0, 0);
  __syncthreads();

  for (int ch = 0; ch < 16; ++ch) {
    const int pb = ch & 1;
    if (ch < 15) STAGE(ch + 1, pb ^ 1);  // in flight across the MFMA block
    __builtin_amdgcn_s_setprio(1);
#pragma unroll
    for (int kk = 0; kk < 2; ++kk) {
      v8s af = *(const v8s*)&As[pb][(wm * 2 + kk) * 512 + lane * 8];
#pragma unroll
      for (int ni = 0; ni < 4; ++ni) {
        v8s bfr = *(const v8s*)&Bs[pb][((wn * 4 + ni) * 2 + kk) * 512 + lane * 8];
        acc[ni] = __builtin_amdgcn_mfma_f32_16x16x32_bf16(af, bfr, acc[ni], 0, 0, 0);
      }
    }
    __builtin_amdgcn_s_setprio(0);
    __syncthreads();  // drains this wave's glds16 (vmcnt) + ds_reads (lgkm)
  }

  // ---- in-register cell update: thread owns gates i,f,g,o (ni=gate) at
  // hidden j = nt*32 + wn*16 + c, rows b0 + wm*16 + q*4 + r ----
  float* cl = cbuf + (size_t)layer * (B_ * HD_);
  const size_t bb = (size_t)layer * 2048;
  const int j = nt * 32 + wn * 16 + c;
  float bsum[4];
#pragma unroll
  for (int g4 = 0; g4 < 4; ++g4)
    bsum[g4] = bih[bb + g4 * 512 + j] + bhh[bb + g4 * 512 + j];
#pragma unroll
  for (int r = 0; r < 4; ++r) {
    const int b = b0 + wm * 16 + q * 4 + r;
    float iv = acc[0][r] + bsum[0];
    float fv = acc[1][r] + bsum[1];
    float gv = acc[2][r] + bsum[2];
    float ov = acc[3][r] + bsum[3];
    size_t off = (size_t)b * HD_ + j;
    float cprev = cl[off];
    float cn = sigm(fv) * cprev + sigm(iv) * tanh_(gv);
    float hn = sigm(ov) * tanh_(cn);
    cl[off] = cn;
    hw[off] = __float2bfloat16(hn);
  }
}

// ---------------- epilogue: w = htt @ lin1^T + lin1b ----------------
__global__ __launch_bounds__(64) void k0_lin1(const bf16* __restrict__ ys,
                                              const float* __restrict__ lin1W,
                                              const float* __restrict__ lin1b,
                                              float* __restrict__ wv) {
  __shared__ float htt[HD_];
  const int b = blockIdx.x, tid = threadIdx.x;
  for (int i = tid; i < HD_; i += 64)
    htt[i] = b2f(ys[((size_t)(T_ - 1) * B_ + b) * HD_ + i]);
  __syncthreads();
  float a = lin1b[tid];
  const float* wr = lin1W + (size_t)tid * HD_;
  for (int k = 0; k < HD_; k += 4) {
    float4 w4 = *(const float4*)(wr + k);
    a += htt[k] * w4.x + htt[k + 1] * w4.y + htt[k + 2] * w4.z + htt[k + 3] * w4.w;
  }
  wv[(size_t)b * 64 + tid] = a;
}

// ---------------- epilogue: conv einsum + attention (per b) ----------------
__global__ __launch_bounds__(256) void k1_attn(const bf16* __restrict__ ys,
                                               const bf16* __restrict__ kTb,
                                               const float* __restrict__ convb,
                                               const float* __restrict__ wv,
                                               float* __restrict__ vbuf) {
  __shared__ ushort HsL[63 * 512];   // relu(H[b]) bf16
  __shared__ ushort kTL[64 * 64];    // kT[t][c] bf16 (t=63 row zero)
  __shared__ float wsh[64];
  __shared__ float cbs[64];
  const int b = blockIdx.x;
  const int tid = threadIdx.x, lane = tid & 63, w = tid >> 6;

  for (int idx = tid; idx < 63 * 64; idx += 256) {  // 63 rows x 64 groups of 8
    int t = idx >> 6, c8 = idx & 63;
    v8s h = *(const v8s*)(ys + ((size_t)t * B_ + b) * HD_ + c8 * 8);
    v8s r;
#pragma unroll
    for (int e = 0; e < 8; ++e) r[e] = (h[e] & (short)0x8000) ? (short)0 : h[e];
    *(v8s*)&HsL[t * 512 + c8 * 8] = r;
  }
  for (int idx = tid; idx < 512; idx += 256)
    *(v8s*)&kTL[idx * 8] = *(const v8s*)(kTb + idx * 8);
  if (tid < 64) { wsh[tid] = wv[(size_t)b * 64 + tid]; cbs[tid] = convb[tid]; }
  __syncthreads();

  const int ci = lane >> 3, fi = lane & 7;
#pragma unroll
  for (int fgi = 0; fgi < 2; ++fgi) {
    const int fg = w * 2 + fgi, f0 = fg << 6;
    float acc[8][8];
#pragma unroll
    for (int i = 0; i < 8; ++i)
#pragma unroll
      for (int jx = 0; jx < 8; ++jx) acc[i][jx] = 0.f;
    for (int t = 0; t < 63; ++t) {
      v8s k8 = *(const v8s*)&kTL[t * 64 + ci * 8];
      v8s h8 = *(const v8s*)&HsL[t * 512 + f0 + fi * 8];
      float av[8], hv[8];
#pragma unroll
      for (int e = 0; e < 8; ++e) { av[e] = bu2f((ushort)k8[e]); hv[e] = bu2f((ushort)h8[e]); }
#pragma unroll
      for (int i = 0; i < 8; ++i)
#pragma unroll
        for (int jx = 0; jx < 8; ++jx) acc[i][jx] += av[i] * hv[jx];
    }
#pragma unroll
    for (int i = 0; i < 8; ++i)
#pragma unroll
      for (int jx = 0; jx < 8; ++jx)
        acc[i][jx] = fmaxf(acc[i][jx] + cbs[ci * 8 + i], 0.f);

    float vp[8];
#pragma unroll
    for (int jx = 0; jx < 8; ++jx) vp[jx] = 0.f;
#pragma unroll
    for (int i = 0; i < 8; ++i) {
      float sp = 0.f;
#pragma unroll
      for (int jx = 0; jx < 8; ++jx) sp += acc[i][jx] * wsh[fi * 8 + jx];
      sp += __shfl_xor(sp, 1); sp += __shfl_xor(sp, 2); sp += __shfl_xor(sp, 4);
      float al = sigm(sp);
#pragma unroll
      for (int jx = 0; jx < 8; ++jx) vp[jx] += al * acc[i][jx];
    }
#pragma unroll
    for (int jx = 0; jx < 8; ++jx) {
      vp[jx] += __shfl_xor(vp[jx], 8);
      vp[jx] += __shfl_xor(vp[jx], 16);
      vp[jx] += __shfl_xor(vp[jx], 32);
    }
    if (ci == 0)
#pragma unroll
      for (int jx = 0; jx < 8; ++jx)
        atomicAdd(&vbuf[(size_t)b * 64 + fi * 8 + jx], vp[jx]);
  }
}

// ---------------- epilogue: out[b] = [htt,v] . fw + fw[576] ----------------
__global__ __launch_bounds__(64) void k3_out(const bf16* __restrict__ ys,
                                             const float* __restrict__ vbuf,
                                             const float* __restrict__ fw,
                                             float* __restrict__ out) {
  const int b = blockIdx.x, tid = threadIdx.x;
  v8s h = *(const v8s*)(ys + ((size_t)(T_ - 1) * B_ + b) * HD_ + tid * 8);
  const float4 w4a = *(const float4*)(fw + tid * 8);
  const float4 w4b = *(const float4*)(fw + tid * 8 + 4);
  float a = bu2f((ushort)h[0]) * w4a.x + bu2f((ushort)h[1]) * w4a.y +
            bu2f((ushort)h[2]) * w4a.z + bu2f((ushort)h[3]) * w4a.w +
            bu2f((ushort)h[4]) * w4b.x + bu2f((ushort)h[5]) * w4b.y +
            bu2f((ushort)h[6]) * w4b.z + bu2f((ushort)h[7]) * w4b.w;
  a += vbuf[(size_t)b * 64 + tid] * fw[512 + tid];
  for (int m = 1; m < 64; m <<= 1) a += __shfl_xor(a, m);
  if (tid == 0) out[b] = a + fw[576];
}

// ---------------- launch ----------------
extern "C" void kernel_launch(void* const* d_in, const int* in_sizes, int n_in,
                              void* d_out, int out_size, void* d_ws, size_t ws_size,
                              hipStream_t stream) {
  const float* x     = (const float*)d_in[0];
  const float* Wih   = (const float*)d_in[1];
  const float* Whh   = (const float*)d_in[2];
  const float* bih   = (const float*)d_in[3];
  const float* bhh   = (const float*)d_in[4];
  const float* convW = (const float*)d_in[5];
  const float* convb = (const float*)d_in[6];
  const float* lin1W = (const float*)d_in[7];
  const float* lin1b = (const float*)d_in[8];
  const float* lin2W = (const float*)d_in[9];
  const float* lin2b = (const float*)d_in[10];
  const float* outW  = (const float*)d_in[11];
  const float* outb  = (const float*)d_in[12];

  char* ws = (char*)d_ws;
  bf16*  ys   = (bf16*)(ws + O_YS);
  bf16*  hbuf = (bf16*)(ws + O_HB);
  float* cbuf = (float*)(ws + O_CB);
  bf16*  zp   = (bf16*)(ws + O_ZP);
  float* wv   = (float*)(ws + O_WV);
  float* vbuf = (float*)(ws + O_VB);
  bf16*  Wbuf = (bf16*)(ws + O_WB);
  bf16*  kTb  = (bf16*)(ws + O_KT);
  float* fwv  = (float*)(ws + O_FW);
  bf16*  xb   = (bf16*)(ws + O_XB);

  hipMemsetAsync(hbuf, 0, SZ_HB, stream);
  hipMemsetAsync(cbuf, 0, SZ_CB, stream);
  hipMemsetAsync((void*)zp, 0, SZ_ZP, stream);
  hipMemsetAsync(vbuf, 0, SZ_VB, stream);

  prep_w<<<3072, 256, 0, stream>>>(Wih, Whh, Wbuf);
  prep_x<<<16384, 256, 0, stream>>>(x, xb);
  prep_kt<<<16, 256, 0, stream>>>(convW, kTb);
  prep_fw<<<10, 64, 0, stream>>>(lin2W, lin2b, outW, outb, fwv);

  // diagonal wavefront: stage s runs cells (l, t=s-l) for active layers
  for (int s = 0; s < T_ + 3 - 1; ++s) {
    int llo = (s > T_ - 1) ? (s - (T_ - 1)) : 0;
    int lhi = (s < 2) ? s : 2;
    int cnt = lhi - llo + 1;
    lstm_stage<<<cnt * 256, 512, 0, stream>>>(xb, Wbuf, bih, bhh, ys, hbuf,
                                              cbuf, zp, s, llo);
  }

  k0_lin1<<<B_, 64, 0, stream>>>(ys, lin1W, lin1b, wv);
  k1_attn<<<B_, 256, 0, stream>>>(ys, kTb, convb, wv, vbuf);
  k3_out<<<B_, 64, 0, stream>>>(ys, vbuf, fwv, (float*)d_out);
}